// Round 1
// baseline (270.137 us; speedup 1.0000x reference)
//
#include <hip/hip_runtime.h>

// Problem constants (from reference): N=8, H=512, W=512, K=8, V=100000, F=200000.
// Outputs (flat-concatenated in d_out, all f32):
//   images        : (N,H,W,4)    = npix*4 floats
//   pixel_coords  : (N,H,W,K,3)  = npix*24 floats
//   pixel_normals : (N,H,W,K,3)  = npix*24 floats

#define KF 8   // faces per pixel

// ---------------------------------------------------------------------------
// Kernel 1: build interleaved per-face table in d_ws:
//   table[f] = { cx, cy, cz, nx } { ny, nz, 0, 0 }   (32 B per face)
// One 64B line holds both centroid and normal -> single-line gathers later.
// ---------------------------------------------------------------------------
__global__ void build_face_table_kernel(const float* __restrict__ verts,
                                        const int* __restrict__ faces,
                                        const float* __restrict__ fnorm,
                                        float4* __restrict__ table,
                                        int F) {
    int f = blockIdx.x * blockDim.x + threadIdx.x;
    if (f >= F) return;
    int i0 = faces[3 * f + 0];
    int i1 = faces[3 * f + 1];
    int i2 = faces[3 * f + 2];
    const float inv3 = 1.0f / 3.0f;
    float cx = (verts[3 * i0 + 0] + verts[3 * i1 + 0] + verts[3 * i2 + 0]) * inv3;
    float cy = (verts[3 * i0 + 1] + verts[3 * i1 + 1] + verts[3 * i2 + 1]) * inv3;
    float cz = (verts[3 * i0 + 2] + verts[3 * i1 + 2] + verts[3 * i2 + 2]) * inv3;
    float nx = fnorm[3 * f + 0];
    float ny = fnorm[3 * f + 1];
    float nz = fnorm[3 * f + 2];
    table[2 * f + 0] = make_float4(cx, cy, cz, nx);
    table[2 * f + 1] = make_float4(ny, nz, 0.0f, 0.0f);
}

// ---------------------------------------------------------------------------
// Kernel 2 (fast path): one thread per pixel, gathers from the packed table.
// ---------------------------------------------------------------------------
__global__ void __launch_bounds__(256) shade_table_kernel(
    const int* __restrict__ p2f,
    const float* __restrict__ texels,
    const float4* __restrict__ table,
    float4* __restrict__ images,    // npix float4
    float4* __restrict__ coords,    // npix*6 float4
    float4* __restrict__ normals,   // npix*6 float4
    int npix) {
    int p = blockIdx.x * blockDim.x + threadIdx.x;
    if (p >= npix) return;

    const int4* pf = (const int4*)(p2f + (size_t)p * KF);
    int4 fa = pf[0];
    int4 fb = pf[1];
    int fid[KF] = {fa.x, fa.y, fa.z, fa.w, fb.x, fb.y, fb.z, fb.w};

    float c[24], n[24];
#pragma unroll
    for (int k = 0; k < KF; ++k) {
        int f = fid[k];
        int fs = f < 0 ? 0 : f;               // safe index (predicated, no branch)
        float4 t0 = table[(size_t)(2 * fs) + 0];
        float4 t1 = table[(size_t)(2 * fs) + 1];
        bool live = f >= 0;
        c[3 * k + 0] = live ? t0.x : 0.0f;
        c[3 * k + 1] = live ? t0.y : 0.0f;
        c[3 * k + 2] = live ? t0.z : 0.0f;
        n[3 * k + 0] = live ? t0.w : 0.0f;
        n[3 * k + 1] = live ? t1.x : 0.0f;
        n[3 * k + 2] = live ? t1.y : 0.0f;
    }

    size_t ob = (size_t)p * 6;
#pragma unroll
    for (int q = 0; q < 6; ++q)
        coords[ob + q] = make_float4(c[4 * q + 0], c[4 * q + 1], c[4 * q + 2], c[4 * q + 3]);
#pragma unroll
    for (int q = 0; q < 6; ++q)
        normals[ob + q] = make_float4(n[4 * q + 0], n[4 * q + 1], n[4 * q + 2], n[4 * q + 3]);

    float4 img;
    if (fid[0] >= 0) {
        // texels[p, k=0, :] ; 16B-aligned (p*24 floats = 96 B); 4th lane harmless over-read (in-bounds)
        float4 t = *(const float4*)(texels + (size_t)p * (KF * 3));
        img = make_float4(t.x, t.y, t.z, 1.0f);
    } else {
        img = make_float4(1.0f, 1.0f, 1.0f, 0.0f);
    }
    images[p] = img;
}

// ---------------------------------------------------------------------------
// Kernel 2 (fallback, if ws too small): gather faces/verts/normals inline.
// ---------------------------------------------------------------------------
__global__ void __launch_bounds__(256) shade_inline_kernel(
    const int* __restrict__ p2f,
    const float* __restrict__ texels,
    const float* __restrict__ verts,
    const int* __restrict__ faces,
    const float* __restrict__ fnorm,
    float4* __restrict__ images,
    float4* __restrict__ coords,
    float4* __restrict__ normals,
    int npix) {
    int p = blockIdx.x * blockDim.x + threadIdx.x;
    if (p >= npix) return;

    const int4* pf = (const int4*)(p2f + (size_t)p * KF);
    int4 fa = pf[0];
    int4 fb = pf[1];
    int fid[KF] = {fa.x, fa.y, fa.z, fa.w, fb.x, fb.y, fb.z, fb.w};

    float c[24], n[24];
#pragma unroll
    for (int k = 0; k < KF; ++k) {
        int f = fid[k];
        float cx = 0.f, cy = 0.f, cz = 0.f, nx = 0.f, ny = 0.f, nz = 0.f;
        if (f >= 0) {
            int i0 = faces[3 * f + 0];
            int i1 = faces[3 * f + 1];
            int i2 = faces[3 * f + 2];
            const float inv3 = 1.0f / 3.0f;
            cx = (verts[3 * i0 + 0] + verts[3 * i1 + 0] + verts[3 * i2 + 0]) * inv3;
            cy = (verts[3 * i0 + 1] + verts[3 * i1 + 1] + verts[3 * i2 + 1]) * inv3;
            cz = (verts[3 * i0 + 2] + verts[3 * i1 + 2] + verts[3 * i2 + 2]) * inv3;
            nx = fnorm[3 * f + 0];
            ny = fnorm[3 * f + 1];
            nz = fnorm[3 * f + 2];
        }
        c[3 * k + 0] = cx; c[3 * k + 1] = cy; c[3 * k + 2] = cz;
        n[3 * k + 0] = nx; n[3 * k + 1] = ny; n[3 * k + 2] = nz;
    }

    size_t ob = (size_t)p * 6;
#pragma unroll
    for (int q = 0; q < 6; ++q)
        coords[ob + q] = make_float4(c[4 * q + 0], c[4 * q + 1], c[4 * q + 2], c[4 * q + 3]);
#pragma unroll
    for (int q = 0; q < 6; ++q)
        normals[ob + q] = make_float4(n[4 * q + 0], n[4 * q + 1], n[4 * q + 2], n[4 * q + 3]);

    float4 img;
    if (fid[0] >= 0) {
        float4 t = *(const float4*)(texels + (size_t)p * (KF * 3));
        img = make_float4(t.x, t.y, t.z, 1.0f);
    } else {
        img = make_float4(1.0f, 1.0f, 1.0f, 0.0f);
    }
    images[p] = img;
}

extern "C" void kernel_launch(void* const* d_in, const int* in_sizes, int n_in,
                              void* d_out, int out_size, void* d_ws, size_t ws_size,
                              hipStream_t stream) {
    const float* verts = (const float*)d_in[0];
    const int* faces = (const int*)d_in[1];
    const float* fnorm = (const float*)d_in[2];
    const int* p2f = (const int*)d_in[3];
    const float* texels = (const float*)d_in[4];

    const int F = in_sizes[1] / 3;
    const int npix = in_sizes[3] / KF;   // N*H*W

    float* out = (float*)d_out;
    float4* images = (float4*)out;                                 // npix*4 floats
    float4* coords = (float4*)(out + (size_t)npix * 4);            // npix*24 floats
    float4* normals = (float4*)(out + (size_t)npix * 4 + (size_t)npix * 24);

    const size_t ws_needed = (size_t)F * 2 * sizeof(float4);       // 6.4 MB

    dim3 blk(256);
    dim3 grid_pix((npix + 255) / 256);

    if (ws_size >= ws_needed) {
        float4* table = (float4*)d_ws;
        dim3 grid_f((F + 255) / 256);
        build_face_table_kernel<<<grid_f, blk, 0, stream>>>(verts, faces, fnorm, table, F);
        shade_table_kernel<<<grid_pix, blk, 0, stream>>>(p2f, texels, table,
                                                         images, coords, normals, npix);
    } else {
        shade_inline_kernel<<<grid_pix, blk, 0, stream>>>(p2f, texels, verts, faces, fnorm,
                                                          images, coords, normals, npix);
    }
}